// Round 4
// baseline (577.686 us; speedup 1.0000x reference)
//
#include <hip/hip_runtime.h>

#define N_NODES 5000
#define NH 8

typedef unsigned short u16;
typedef short bf16x8 __attribute__((ext_vector_type(8)));
typedef float f32x4 __attribute__((ext_vector_type(4)));

static __device__ __forceinline__ float selu_f(float x) {
    const float sc = 1.0507009873554805f;
    const float al = 1.6732632423543772f;
    return x > 0.f ? sc * x : sc * al * (__expf(x) - 1.f);
}

static __device__ __forceinline__ u16 f2bf(float x) {
    union { float f; unsigned u; } v; v.f = x;
    unsigned r = v.u + 0x7fff + ((v.u >> 16) & 1);
    return (u16)(r >> 16);
}

static __device__ __forceinline__ float bf2f(unsigned hi16) {
    union { unsigned u; float f; } v; v.u = hi16 << 16;
    return v.f;
}

// ---------------- CSR build ----------------
__global__ void k_count(const int* __restrict__ ei, int* cnt, int E, int Esz) {
    int e = blockIdx.x * 256 + threadIdx.x;
    if (e >= Esz) return;
    int dst = (e < E) ? ei[E + e] : (e - E);
    atomicAdd(&cnt[dst], 1);
}

__global__ void k_scan(const int* __restrict__ cnt, int* __restrict__ rowp, int n) {
    __shared__ int buf[1024];
    __shared__ int carry;
    int t = threadIdx.x;
    if (t == 0) { carry = 0; rowp[0] = 0; }
    __syncthreads();
    for (int base = 0; base < n; base += 1024) {
        int v = (base + t < n) ? cnt[base + t] : 0;
        buf[t] = v;
        __syncthreads();
        for (int off = 1; off < 1024; off <<= 1) {
            int x = (t >= off) ? buf[t - off] : 0;
            __syncthreads();
            buf[t] += x;
            __syncthreads();
        }
        if (base + t < n) rowp[base + t + 1] = carry + buf[t];
        __syncthreads();
        if (t == 0) carry += buf[1023];
        __syncthreads();
    }
}

__global__ void k_fill(const int* __restrict__ ei, const int* __restrict__ rowp,
                       int* cur, int* ssrc, int E, int Esz) {
    int e = blockIdx.x * 256 + threadIdx.x;
    if (e >= Esz) return;
    int src, dst;
    if (e < E) { src = ei[e]; dst = ei[E + e]; }
    else       { src = e - E; dst = src; }
    int pos = rowp[dst] + atomicAdd(&cur[dst], 1);
    ssrc[pos] = src;
}

// ---------------- feat0 = selu(data @ W0 + b0), and c0 = data[:, :2] ----------------
__global__ void k_feat0(const float* __restrict__ data, const float* __restrict__ W0,
                        const float* __restrict__ b0, float* __restrict__ f0,
                        float* __restrict__ c0) {
    int n = blockIdx.x;
    int t = threadIdx.x;   // 256
    __shared__ float d[10];
    if (t < 10) d[t] = data[n * 10 + t];
    __syncthreads();
    float acc = b0[t];
    #pragma unroll
    for (int k = 0; k < 10; ++k) acc += d[k] * W0[k * 256 + t];
    f0[(size_t)n * 256 + t] = selu_f(acc);
    if (t < 2) c0[n * 2 + t] = d[t];
}

// ---------------- assemble af = [p0, p1, ..., feat] (fp32) + afb (bf16, k-padded) ----------------
__global__ void k_assemble(float* __restrict__ af, u16* __restrict__ afb,
                           const float* p0, const float* p1, const float* p2, const float* p3,
                           int np, const float* __restrict__ feat, int FC, int K, int Kp) {
    int n = blockIdx.x, t = threadIdx.x;
    float* row = af + (size_t)n * K;
    u16* rowb = afb + (size_t)n * Kp;
    for (int c = t; c < Kp; c += 256) {
        float v = 0.f;
        if (c < K) {
            if (c < 2 * np) {
                const float* p = (c < 2) ? p0 : (c < 4) ? p1 : (c < 6) ? p2 : p3;
                v = p[n * 2 + (c & 1)];
            } else {
                v = feat[(size_t)n * FC + (c - 2 * np)];
            }
            row[c] = v;
        }
        rowb[c] = f2bf(v);
    }
}

// ---------------- fold: folded[k,h] = sum_c W[k, h*C+c]*a[h,c]  (wave per k, fp32) ----------------
__global__ void k_fold2(const float* __restrict__ W, const float* __restrict__ a_s,
                        const float* __restrict__ a_d, float* __restrict__ fs,
                        float* __restrict__ fd, int K, int C) {
    int k = blockIdx.x;
    int lane = threadIdx.x;   // 64
    float s[8] = {0.f,0.f,0.f,0.f,0.f,0.f,0.f,0.f};
    float d[8] = {0.f,0.f,0.f,0.f,0.f,0.f,0.f,0.f};
    const float* wr = W + (size_t)k * 8 * C;
    for (int c = lane; c < C; c += 64) {
        #pragma unroll
        for (int h = 0; h < 8; ++h) {
            float w = wr[h * C + c];
            s[h] += w * a_s[h * C + c];
            d[h] += w * a_d[h * C + c];
        }
    }
    #pragma unroll
    for (int off = 32; off >= 1; off >>= 1) {
        #pragma unroll
        for (int h = 0; h < 8; ++h) {
            s[h] += __shfl_xor(s[h], off);
            d[h] += __shfl_xor(d[h], off);
        }
    }
    if (lane == 0) {
        #pragma unroll
        for (int h = 0; h < 8; ++h) { fs[k * 8 + h] = s[h]; fd[k * 8 + h] = d[h]; }
    }
}

// ---------------- e_s/e_d = af @ [fs|fd]  (block per 16 nodes, LDS tiled, fp32) ----------------
__global__ __launch_bounds__(256) void k_e2(const float* __restrict__ af,
                                            const float* __restrict__ fs,
                                            const float* __restrict__ fd,
                                            float* __restrict__ es, float* __restrict__ ed,
                                            int K) {
    __shared__ float As[16][65];
    __shared__ float Fs[64][16];
    int tid = threadIdx.x;
    int n0 = blockIdx.x * 16;
    int i = tid >> 4, j = tid & 15;
    float acc = 0.f;
    for (int k0 = 0; k0 < K; k0 += 64) {
        for (int idx = tid; idx < 1024; idx += 256) {
            int r = idx >> 6, cc = idx & 63;
            int gk = k0 + cc, gn = n0 + r;
            As[r][cc] = (gk < K && gn < N_NODES) ? af[(size_t)gn * K + gk] : 0.f;
        }
        for (int idx = tid; idx < 1024; idx += 256) {
            int cc = idx >> 4, jj = idx & 15;
            int gk = k0 + cc;
            float v = 0.f;
            if (gk < K) v = (jj < 8) ? fs[gk * 8 + jj] : fd[gk * 8 + (jj - 8)];
            Fs[cc][jj] = v;
        }
        __syncthreads();
        #pragma unroll 8
        for (int cc = 0; cc < 64; ++cc) acc += As[i][cc] * Fs[cc][j];
        __syncthreads();
    }
    int n = n0 + i;
    if (n < N_NODES) {
        if (j < 8) es[n * 8 + j] = acc;
        else       ed[n * 8 + (j - 8)] = acc;
    }
}

// ---------------- W [K][8C] fp32 -> Wt2 [C][8*Kp] bf16: Wt2[c, h*Kp+k] = W[k, h*C+c] ----------------
__global__ __launch_bounds__(256) void k_wtr2(const float* __restrict__ W, u16* __restrict__ Wt2,
                                              int K, int Kp, int C) {
    __shared__ float tile[32][33];
    int c0 = blockIdx.x * 32;
    int j0 = blockIdx.y * 32;           // j = h*Kp + k; Kp % 32 == 0 so single h per tile
    int h = j0 / Kp, k0 = j0 % Kp;
    int tid = threadIdx.x;
    for (int idx = tid; idx < 1024; idx += 256) {
        int kr = idx >> 5, cc = idx & 31;
        int gk = k0 + kr;
        tile[kr][cc] = (gk < K) ? W[(size_t)gk * (8 * C) + h * C + c0 + cc] : 0.f;
    }
    __syncthreads();
    int KK = 8 * Kp;
    for (int idx = tid; idx < 1024; idx += 256) {
        int cr = idx >> 5, kc = idx & 31;
        Wt2[(size_t)(c0 + cr) * KK + j0 + kc] = f2bf(tile[kc][cr]);
    }
}

// ---------------- per-node softmax over incoming edges (wave per node, fp32) ----------------
__global__ void k_alpha(const float* __restrict__ es, const float* __restrict__ ed,
                        const int* __restrict__ rowp, const int* __restrict__ ssrc,
                        float* __restrict__ alpha, float* __restrict__ wsum) {
    int wid = (blockIdx.x * blockDim.x + threadIdx.x) >> 6;
    int lane = threadIdx.x & 63;
    if (wid >= N_NODES) return;
    int n = wid;
    int s0 = rowp[n], deg = rowp[n + 1] - s0;
    int h = lane & 7, ei = lane >> 3;
    float edh = ed[n * 8 + h];
    float m = -1e30f;
    for (int b = 0; b < deg; b += 8) {
        int e = b + ei;
        if (e < deg) {
            int src = ssrc[s0 + e];
            float x = es[src * 8 + h] + edh;
            x = x > 0.f ? x : 0.2f * x;
            m = fmaxf(m, x);
        }
    }
    m = fmaxf(m, __shfl_xor(m, 8));
    m = fmaxf(m, __shfl_xor(m, 16));
    m = fmaxf(m, __shfl_xor(m, 32));
    float ssum = 0.f;
    for (int b = 0; b < deg; b += 8) {
        int e = b + ei;
        if (e < deg) {
            int src = ssrc[s0 + e];
            float x = es[src * 8 + h] + edh;
            x = x > 0.f ? x : 0.2f * x;
            ssum += __expf(x - m);
        }
    }
    ssum += __shfl_xor(ssum, 8);
    ssum += __shfl_xor(ssum, 16);
    ssum += __shfl_xor(ssum, 32);
    float inv = 1.f / ssum;
    for (int b = 0; b < deg; b += 8) {
        int e = b + ei;
        if (e < deg) {
            int src = ssrc[s0 + e];
            float x = es[src * 8 + h] + edh;
            x = x > 0.f ? x : 0.2f * x;
            float a = __expf(x - m) * inv;
            alpha[(size_t)(s0 + e) * 8 + h] = a;
            float w = a;
            w += __shfl_xor(w, 1);
            w += __shfl_xor(w, 2);
            w += __shfl_xor(w, 4);
            if (h == 0) wsum[s0 + e] = w;
        }
    }
}

// ---------------- g[n, h*Kp+k] = sum_e alpha[e,h]*afb[src,k]; also coords update ----------------
template <int S>
__global__ __launch_bounds__(256) void k_gather_g(const u16* __restrict__ afb,
                            const float* __restrict__ alpha, const float* __restrict__ wsum,
                            const int* __restrict__ rowp, const int* __restrict__ ssrc,
                            const float* __restrict__ cprev, u16* __restrict__ g,
                            float* __restrict__ cnext, int Kp) {
    __shared__ int ls[64];
    __shared__ float la[512];
    __shared__ float lw[64];
    __shared__ float lred[128];
    int n = blockIdx.x, t = threadIdx.x;
    int s0 = rowp[n], s1 = rowp[n + 1];
    float acc[8][S];
    #pragma unroll
    for (int h = 0; h < 8; ++h)
        #pragma unroll
        for (int s = 0; s < S; ++s) acc[h][s] = 0.f;
    float oc0 = 0.f, oc1 = 0.f;
    for (int base = s0; base < s1; base += 64) {
        int ce = min(64, s1 - base);
        for (int i = t; i < ce; i += 256) { ls[i] = ssrc[base + i]; lw[i] = wsum[base + i]; }
        for (int i = t; i < ce * 8; i += 256) la[i] = alpha[(size_t)base * 8 + i];
        __syncthreads();
        for (int e = 0; e < ce; ++e) {
            int src = ls[e];
            const u16* ar = afb + (size_t)src * Kp;
            float a0 = la[e*8+0], a1 = la[e*8+1], a2 = la[e*8+2], a3 = la[e*8+3];
            float a4 = la[e*8+4], a5 = la[e*8+5], a6 = la[e*8+6], a7 = la[e*8+7];
            #pragma unroll
            for (int s = 0; s < S; ++s) {
                int k = t + 256 * s;
                if (k < Kp) {
                    float v = bf2f(ar[k]);
                    acc[0][s] += a0 * v; acc[1][s] += a1 * v;
                    acc[2][s] += a2 * v; acc[3][s] += a3 * v;
                    acc[4][s] += a4 * v; acc[5][s] += a5 * v;
                    acc[6][s] += a6 * v; acc[7][s] += a7 * v;
                }
            }
        }
        if (t < ce) {
            int src = ls[t]; float w = lw[t];
            lred[t] = w * cprev[src * 2];
            lred[64 + t] = w * cprev[src * 2 + 1];
        }
        __syncthreads();
        if (t == 0) {
            for (int i = 0; i < ce; ++i) { oc0 += lred[i]; oc1 += lred[64 + i]; }
        }
        __syncthreads();
    }
    u16* gr = g + (size_t)n * 8 * Kp;
    #pragma unroll
    for (int s = 0; s < S; ++s) {
        int k = t + 256 * s;
        if (k < Kp) {
            #pragma unroll
            for (int h = 0; h < 8; ++h) gr[h * Kp + k] = f2bf(acc[h][s]);
        }
    }
    if (t == 0) {
        oc0 *= 0.025f; oc1 *= 0.025f;   // 0.2 * (1/8)
        float a0 = cprev[n * 2], a1 = cprev[n * 2 + 1];
        cnext[n * 2]     = (a0 == 0.f) ? 0.f : ((a0 == 1.f) ? 1.f : oc0);
        cnext[n * 2 + 1] = (a1 == 1.f) ? 1.f : ((a1 == 0.f) ? 0.f : oc1);
    }
}

// ---------------- fnext = selu((g @ Wt2^T)*0.125 + bias): MFMA, 128x64 tile ----------------
__global__ __launch_bounds__(256) void k_gemm_g(const u16* __restrict__ A,   // [M, KK]
                                                const u16* __restrict__ Bt,  // [NC, KK]
                                                const float* __restrict__ bias,
                                                float* __restrict__ Cf,      // [M, NC]
                                                int M, int KK, int NC) {
    __shared__ u16 As[128 * 32];
    __shared__ u16 Bs[64 * 32];
    int tid = threadIdx.x;
    int wave = tid >> 6, lane = tid & 63;
    int bm = blockIdx.y * 128, bn = blockIdx.x * 64;
    int wm = (wave >> 1) * 64, wn = (wave & 1) * 32;
    int l16 = lane & 15, q = lane >> 4;
    f32x4 acc[4][2] = {};
    for (int k0 = 0; k0 < KK; k0 += 32) {
        #pragma unroll
        for (int it = 0; it < 2; ++it) {
            int seg = tid + it * 256;
            int row = seg >> 2, sq = seg & 3;
            uint4 va = {0u, 0u, 0u, 0u};
            int grow = bm + row;
            if (grow < M) va = *(const uint4*)(A + (size_t)grow * KK + k0 + sq * 8);
            *(uint4*)(As + row * 32 + ((sq ^ (row & 3)) * 8)) = va;
        }
        {
            int row = tid >> 2, sq = tid & 3;
            uint4 vb = *(const uint4*)(Bt + (size_t)(bn + row) * KK + k0 + sq * 8);
            *(uint4*)(Bs + row * 32 + ((sq ^ (row & 3)) * 8)) = vb;
        }
        __syncthreads();
        bf16x8 fa[4], fb[2];
        #pragma unroll
        for (int mi = 0; mi < 4; ++mi) {
            int row = wm + mi * 16 + l16;
            fa[mi] = *(const bf16x8*)(As + row * 32 + ((q ^ (row & 3)) * 8));
        }
        #pragma unroll
        for (int ni = 0; ni < 2; ++ni) {
            int col = wn + ni * 16 + l16;
            fb[ni] = *(const bf16x8*)(Bs + col * 32 + ((q ^ (col & 3)) * 8));
        }
        #pragma unroll
        for (int mi = 0; mi < 4; ++mi)
            #pragma unroll
            for (int ni = 0; ni < 2; ++ni)
                acc[mi][ni] = __builtin_amdgcn_mfma_f32_16x16x32_bf16(fa[mi], fb[ni], acc[mi][ni], 0, 0, 0);
        __syncthreads();
    }
    #pragma unroll
    for (int mi = 0; mi < 4; ++mi) {
        int row0 = bm + wm + mi * 16 + q * 4;
        #pragma unroll
        for (int ni = 0; ni < 2; ++ni) {
            int col = bn + wn + ni * 16 + l16;
            float b = bias[col];
            #pragma unroll
            for (int r = 0; r < 4; ++r) {
                int row = row0 + r;
                if (row < M) Cf[(size_t)row * NC + col] = selu_f(acc[mi][ni][r] * 0.125f + b);
            }
        }
    }
}

// ---------------- layer 4: coords only ----------------
__global__ void k_coords4(const float* __restrict__ wsum, const int* __restrict__ rowp,
                          const int* __restrict__ ssrc, const float* __restrict__ cprev,
                          float* __restrict__ outp) {
    int n = blockIdx.x * 256 + threadIdx.x;
    if (n >= N_NODES) return;
    int s0 = rowp[n], s1 = rowp[n + 1];
    float oc0 = 0.f, oc1 = 0.f;
    for (int s = s0; s < s1; ++s) {
        int src = ssrc[s];
        float w = wsum[s];
        oc0 += w * cprev[src * 2];
        oc1 += w * cprev[src * 2 + 1];
    }
    oc0 *= 0.2f * 0.125f;
    oc1 *= 0.2f * 0.125f;
    float a0 = cprev[n * 2], a1 = cprev[n * 2 + 1];
    outp[n * 2]     = (a0 == 0.f) ? 0.f : ((a0 == 1.f) ? 1.f : oc0);
    outp[n * 2 + 1] = (a1 == 1.f) ? 1.f : ((a1 == 0.f) ? 0.f : oc1);
}

extern "C" void kernel_launch(void* const* d_in, const int* in_sizes, int n_in,
                              void* d_out, int out_size, void* d_ws, size_t ws_size,
                              hipStream_t stream) {
    const float* data = (const float*)d_in[0];
    const int* ei = (const int*)d_in[1];
    const float* W0 = (const float*)d_in[2];
    const float* b0 = (const float*)d_in[3];
    int E = in_sizes[1] / 2;           // 40000
    int Esz = E + N_NODES;             // +self loops

    char* wp = (char*)d_ws;
    size_t off = 0;
    auto alloc = [&](size_t bytes) {
        void* p = wp + off;
        off += (bytes + 1023) & ~(size_t)1023;
        return p;
    };
    u16*   g     = (u16*)alloc((size_t)N_NODES * 8 * 576 * 2);
    u16*   Wt2   = (u16*)alloc((size_t)512 * 8 * 576 * 2);
    float* af    = (float*)alloc((size_t)N_NODES * 516 * 4);
    float* fA    = (float*)alloc((size_t)N_NODES * 512 * 4);
    float* fB    = (float*)alloc((size_t)N_NODES * 512 * 4);
    u16*   afb   = (u16*)alloc((size_t)N_NODES * 576 * 2);
    float* alpha = (float*)alloc((size_t)Esz * 8 * 4);
    float* wsum  = (float*)alloc((size_t)Esz * 4);
    float* es    = (float*)alloc((size_t)N_NODES * 8 * 4);
    float* ebd   = (float*)alloc((size_t)N_NODES * 8 * 4);
    float* fs    = (float*)alloc(516 * 8 * 4);
    float* fd    = (float*)alloc(516 * 8 * 4);
    float* c0    = (float*)alloc(N_NODES * 2 * 4);
    float* c1    = (float*)alloc(N_NODES * 2 * 4);
    float* c2    = (float*)alloc(N_NODES * 2 * 4);
    float* c3    = (float*)alloc(N_NODES * 2 * 4);
    int* cnt  = (int*)alloc(N_NODES * 4);
    int* rowp = (int*)alloc((N_NODES + 1) * 4);
    int* cur  = (int*)alloc(N_NODES * 4);
    int* ssrc = (int*)alloc(Esz * 4);

    hipMemsetAsync(cnt, 0, N_NODES * 4, stream);
    hipMemsetAsync(cur, 0, N_NODES * 4, stream);
    int gE = (Esz + 255) / 256;
    k_count<<<gE, 256, 0, stream>>>(ei, cnt, E, Esz);
    k_scan<<<1, 1024, 0, stream>>>(cnt, rowp, N_NODES);
    k_fill<<<gE, 256, 0, stream>>>(ei, rowp, cur, ssrc, E, Esz);
    k_feat0<<<N_NODES, 256, 0, stream>>>(data, W0, b0, fA, c0);

    struct LP { const float *W, *as, *ad, *bs; int K, C; };
    LP L[4] = {
        {(const float*)d_in[4],  (const float*)d_in[5],  (const float*)d_in[6],  (const float*)d_in[7],  258, 512},
        {(const float*)d_in[8],  (const float*)d_in[9],  (const float*)d_in[10], (const float*)d_in[11], 516, 256},
        {(const float*)d_in[12], (const float*)d_in[13], (const float*)d_in[14], (const float*)d_in[15], 262, 128},
        {(const float*)d_in[16], (const float*)d_in[17], (const float*)d_in[18], (const float*)d_in[19], 136, 20},
    };
    float* cbuf[4] = {c0, c1, c2, c3};
    float* featin[4] = {fA, fB, fA, fB};
    int FC[4] = {256, 512, 256, 128};

    for (int li = 0; li < 4; ++li) {
        LP& lp = L[li];
        const float* p[4] = {nullptr, nullptr, nullptr, nullptr};
        for (int j = 0; j <= li; ++j) p[j] = cbuf[li - j];
        int Kp = ((lp.K + 31) / 32) * 32;
        k_assemble<<<N_NODES, 256, 0, stream>>>(af, afb, p[0], p[1], p[2], p[3], li + 1,
                                                featin[li], FC[li], lp.K, Kp);
        k_fold2<<<lp.K, 64, 0, stream>>>(lp.W, lp.as, lp.ad, fs, fd, lp.K, lp.C);
        k_e2<<<(N_NODES + 15) / 16, 256, 0, stream>>>(af, fs, fd, es, ebd, lp.K);
        if (li < 3)
            k_wtr2<<<dim3(lp.C / 32, (8 * Kp) / 32), 256, 0, stream>>>(lp.W, Wt2, lp.K, Kp, lp.C);
        k_alpha<<<(N_NODES + 3) / 4, 256, 0, stream>>>(es, ebd, rowp, ssrc, alpha, wsum);
        if (li < 3) {
            float* fnext = featin[li + 1];
            if (Kp <= 512)
                k_gather_g<2><<<N_NODES, 256, 0, stream>>>(afb, alpha, wsum, rowp, ssrc,
                                                           cbuf[li], g, cbuf[li + 1], Kp);
            else
                k_gather_g<3><<<N_NODES, 256, 0, stream>>>(afb, alpha, wsum, rowp, ssrc,
                                                           cbuf[li], g, cbuf[li + 1], Kp);
            k_gemm_g<<<dim3(lp.C / 64, (N_NODES + 127) / 128), 256, 0, stream>>>(
                g, Wt2, lp.bs, fnext, N_NODES, 8 * Kp, lp.C);
        } else {
            k_coords4<<<(N_NODES + 255) / 256, 256, 0, stream>>>(wsum, rowp, ssrc, cbuf[3],
                                                                 (float*)d_out);
        }
    }
}

// Round 5
// 464.055 us; speedup vs baseline: 1.2449x; 1.2449x over previous
//
#include <hip/hip_runtime.h>

#define N_NODES 5000
#define NH 8

typedef unsigned short u16;
typedef short bf16x8 __attribute__((ext_vector_type(8)));
typedef float f32x4 __attribute__((ext_vector_type(4)));

static __device__ __forceinline__ float selu_f(float x) {
    const float sc = 1.0507009873554805f;
    const float al = 1.6732632423543772f;
    return x > 0.f ? sc * x : sc * al * (__expf(x) - 1.f);
}

static __device__ __forceinline__ u16 f2bf(float x) {
    union { float f; unsigned u; } v; v.f = x;
    unsigned r = v.u + 0x7fff + ((v.u >> 16) & 1);
    return (u16)(r >> 16);
}

static __device__ __forceinline__ float bf2f(unsigned hi16) {
    union { unsigned u; float f; } v; v.u = hi16 << 16;
    return v.f;
}

// ---------------- CSR build ----------------
__global__ void k_count(const int* __restrict__ ei, int* cnt, int E, int Esz) {
    int e = blockIdx.x * 256 + threadIdx.x;
    if (e >= Esz) return;
    int dst = (e < E) ? ei[E + e] : (e - E);
    atomicAdd(&cnt[dst], 1);
}

// single block, 256 threads, chunked exclusive scan
__global__ void k_scan(const int* __restrict__ cnt, int* __restrict__ rowp, int n) {
    __shared__ int ps[256];
    int t = threadIdx.x;
    int per = (n + 255) / 256;
    int b = t * per;
    int s = 0;
    for (int i = 0; i < per; ++i) { int idx = b + i; if (idx < n) s += cnt[idx]; }
    ps[t] = s;
    __syncthreads();
    for (int off = 1; off < 256; off <<= 1) {
        int v = (t >= off) ? ps[t - off] : 0;
        __syncthreads();
        ps[t] += v;
        __syncthreads();
    }
    int run = (t == 0) ? 0 : ps[t - 1];
    for (int i = 0; i < per; ++i) {
        int idx = b + i;
        if (idx < n) { rowp[idx] = run; run += cnt[idx]; }
    }
    if (t == 255) rowp[n] = run;
}

__global__ void k_fill(const int* __restrict__ ei, const int* __restrict__ rowp,
                       int* cur, int* ssrc, int E, int Esz) {
    int e = blockIdx.x * 256 + threadIdx.x;
    if (e >= Esz) return;
    int src, dst;
    if (e < E) { src = ei[e]; dst = ei[E + e]; }
    else       { src = e - E; dst = src; }
    int pos = rowp[dst] + atomicAdd(&cur[dst], 1);
    ssrc[pos] = src;
}

// ---------------- feat0 = selu(data @ W0 + b0), and c0 = data[:, :2] ----------------
__global__ void k_feat0(const float* __restrict__ data, const float* __restrict__ W0,
                        const float* __restrict__ b0, float* __restrict__ f0,
                        float* __restrict__ c0) {
    int n = blockIdx.x;
    int t = threadIdx.x;   // 256
    __shared__ float d[10];
    if (t < 10) d[t] = data[n * 10 + t];
    __syncthreads();
    float acc = b0[t];
    #pragma unroll
    for (int k = 0; k < 10; ++k) acc += d[k] * W0[k * 256 + t];
    f0[(size_t)n * 256 + t] = selu_f(acc);
    if (t < 2) c0[n * 2 + t] = d[t];
}

// ---------------- fold: folded[k,h] = sum_c W[k, h*C+c]*a[h,c]  (wave per k, fp32) ----------------
__global__ void k_fold2(const float* __restrict__ W, const float* __restrict__ a_s,
                        const float* __restrict__ a_d, float* __restrict__ fs,
                        float* __restrict__ fd, int K, int C) {
    int k = blockIdx.x;
    int lane = threadIdx.x;   // 64
    float s[8] = {0.f,0.f,0.f,0.f,0.f,0.f,0.f,0.f};
    float d[8] = {0.f,0.f,0.f,0.f,0.f,0.f,0.f,0.f};
    const float* wr = W + (size_t)k * 8 * C;
    for (int c = lane; c < C; c += 64) {
        #pragma unroll
        for (int h = 0; h < 8; ++h) {
            float w = wr[h * C + c];
            s[h] += w * a_s[h * C + c];
            d[h] += w * a_d[h * C + c];
        }
    }
    #pragma unroll
    for (int off = 32; off >= 1; off >>= 1) {
        #pragma unroll
        for (int h = 0; h < 8; ++h) {
            s[h] += __shfl_xor(s[h], off);
            d[h] += __shfl_xor(d[h], off);
        }
    }
    if (lane == 0) {
        #pragma unroll
        for (int h = 0; h < 8; ++h) { fs[k * 8 + h] = s[h]; fd[k * 8 + h] = d[h]; }
    }
}

// ---------------- fused assemble + e: builds af tile in LDS, writes afb, computes es/ed ----------------
__global__ __launch_bounds__(256) void k_ae(const float* p0, const float* p1,
                                            const float* p2, const float* p3,
                                            int np, const float* __restrict__ feat, int FC,
                                            int K, int Kp,
                                            const float* __restrict__ fs,
                                            const float* __restrict__ fd,
                                            u16* __restrict__ afb,
                                            float* __restrict__ es, float* __restrict__ ed) {
    __shared__ float As[16][66];
    __shared__ float Fs[64][16];
    int tid = threadIdx.x;
    int n0 = blockIdx.x * 16;
    int i = tid >> 4, j = tid & 15;
    float acc = 0.f;
    for (int k0 = 0; k0 < Kp; k0 += 64) {
        for (int idx = tid; idx < 1024; idx += 256) {
            int r = idx >> 6, cc = idx & 63;
            int c = k0 + cc, n = n0 + r;
            float v = 0.f;
            if (n < N_NODES && c < K) {
                if (c < 2 * np) {
                    const float* p = (c < 2) ? p0 : (c < 4) ? p1 : (c < 6) ? p2 : p3;
                    v = p[n * 2 + (c & 1)];
                } else {
                    v = feat[(size_t)n * FC + (c - 2 * np)];
                }
            }
            As[r][cc] = v;
            if (n < N_NODES && c < Kp) afb[(size_t)n * Kp + c] = f2bf(v);
        }
        for (int idx = tid; idx < 1024; idx += 256) {
            int cc = idx >> 4, jj = idx & 15;
            int gk = k0 + cc;
            float v = 0.f;
            if (gk < K) v = (jj < 8) ? fs[gk * 8 + jj] : fd[gk * 8 + (jj - 8)];
            Fs[cc][jj] = v;
        }
        __syncthreads();
        #pragma unroll 8
        for (int cc = 0; cc < 64; ++cc) acc += As[i][cc] * Fs[cc][j];
        __syncthreads();
    }
    int n = n0 + i;
    if (n < N_NODES) {
        if (j < 8) es[n * 8 + j] = acc;
        else       ed[n * 8 + (j - 8)] = acc;
    }
}

// ---------------- W [K][8C] fp32 -> Wt2 [C][8*Kp] bf16: Wt2[c, h*Kp+k] = W[k, h*C+c] ----------------
__global__ __launch_bounds__(256) void k_wtr2(const float* __restrict__ W, u16* __restrict__ Wt2,
                                              int K, int Kp, int C) {
    __shared__ float tile[32][33];
    int c0 = blockIdx.x * 32;
    int j0 = blockIdx.y * 32;           // j = h*Kp + k; Kp % 32 == 0 so single h per tile
    int h = j0 / Kp, k0 = j0 % Kp;
    int tid = threadIdx.x;
    for (int idx = tid; idx < 1024; idx += 256) {
        int kr = idx >> 5, cc = idx & 31;
        int gk = k0 + kr;
        tile[kr][cc] = (gk < K) ? W[(size_t)gk * (8 * C) + h * C + c0 + cc] : 0.f;
    }
    __syncthreads();
    int KK = 8 * Kp;
    for (int idx = tid; idx < 1024; idx += 256) {
        int cr = idx >> 5, kc = idx & 31;
        Wt2[(size_t)(c0 + cr) * KK + j0 + kc] = f2bf(tile[kc][cr]);
    }
}

// ---------------- per-node softmax over incoming edges (wave per node, fp32) ----------------
__global__ void k_alpha(const float* __restrict__ es, const float* __restrict__ ed,
                        const int* __restrict__ rowp, const int* __restrict__ ssrc,
                        float* __restrict__ alpha, float* __restrict__ wsum) {
    int wid = (blockIdx.x * blockDim.x + threadIdx.x) >> 6;
    int lane = threadIdx.x & 63;
    if (wid >= N_NODES) return;
    int n = wid;
    int s0 = rowp[n], deg = rowp[n + 1] - s0;
    int h = lane & 7, ei = lane >> 3;
    float edh = ed[n * 8 + h];
    float m = -1e30f;
    for (int b = 0; b < deg; b += 8) {
        int e = b + ei;
        if (e < deg) {
            int src = ssrc[s0 + e];
            float x = es[src * 8 + h] + edh;
            x = x > 0.f ? x : 0.2f * x;
            m = fmaxf(m, x);
        }
    }
    m = fmaxf(m, __shfl_xor(m, 8));
    m = fmaxf(m, __shfl_xor(m, 16));
    m = fmaxf(m, __shfl_xor(m, 32));
    float ssum = 0.f;
    for (int b = 0; b < deg; b += 8) {
        int e = b + ei;
        if (e < deg) {
            int src = ssrc[s0 + e];
            float x = es[src * 8 + h] + edh;
            x = x > 0.f ? x : 0.2f * x;
            ssum += __expf(x - m);
        }
    }
    ssum += __shfl_xor(ssum, 8);
    ssum += __shfl_xor(ssum, 16);
    ssum += __shfl_xor(ssum, 32);
    float inv = 1.f / ssum;
    for (int b = 0; b < deg; b += 8) {
        int e = b + ei;
        if (e < deg) {
            int src = ssrc[s0 + e];
            float x = es[src * 8 + h] + edh;
            x = x > 0.f ? x : 0.2f * x;
            float a = __expf(x - m) * inv;
            alpha[(size_t)(s0 + e) * 8 + h] = a;
            float w = a;
            w += __shfl_xor(w, 1);
            w += __shfl_xor(w, 2);
            w += __shfl_xor(w, 4);
            if (h == 0) wsum[s0 + e] = w;
        }
    }
}

// ---------------- g[n, h*Kp+k] = sum_e alpha[e,h]*afb[src,k]; also coords update ----------------
template <int S>
__global__ __launch_bounds__(256) void k_gather_g(const u16* __restrict__ afb,
                            const float* __restrict__ alpha, const float* __restrict__ wsum,
                            const int* __restrict__ rowp, const int* __restrict__ ssrc,
                            const float* __restrict__ cprev, u16* __restrict__ g,
                            float* __restrict__ cnext, int Kp) {
    __shared__ int ls[64];
    __shared__ float la[512];
    __shared__ float lw[64];
    __shared__ float lred[128];
    int n = blockIdx.x, t = threadIdx.x;
    int s0 = rowp[n], s1 = rowp[n + 1];
    float acc[8][S];
    #pragma unroll
    for (int h = 0; h < 8; ++h)
        #pragma unroll
        for (int s = 0; s < S; ++s) acc[h][s] = 0.f;
    float oc0 = 0.f, oc1 = 0.f;
    for (int base = s0; base < s1; base += 64) {
        int ce = min(64, s1 - base);
        for (int i = t; i < ce; i += 256) { ls[i] = ssrc[base + i]; lw[i] = wsum[base + i]; }
        for (int i = t; i < ce * 8; i += 256) la[i] = alpha[(size_t)base * 8 + i];
        __syncthreads();
        for (int e = 0; e < ce; ++e) {
            int src = ls[e];
            const u16* ar = afb + (size_t)src * Kp;
            float a0 = la[e*8+0], a1 = la[e*8+1], a2 = la[e*8+2], a3 = la[e*8+3];
            float a4 = la[e*8+4], a5 = la[e*8+5], a6 = la[e*8+6], a7 = la[e*8+7];
            #pragma unroll
            for (int s = 0; s < S; ++s) {
                int k = t + 256 * s;
                if (k < Kp) {
                    float v = bf2f(ar[k]);
                    acc[0][s] += a0 * v; acc[1][s] += a1 * v;
                    acc[2][s] += a2 * v; acc[3][s] += a3 * v;
                    acc[4][s] += a4 * v; acc[5][s] += a5 * v;
                    acc[6][s] += a6 * v; acc[7][s] += a7 * v;
                }
            }
        }
        if (t < ce) {
            int src = ls[t]; float w = lw[t];
            lred[t] = w * cprev[src * 2];
            lred[64 + t] = w * cprev[src * 2 + 1];
        }
        __syncthreads();
        if (t == 0) {
            for (int i = 0; i < ce; ++i) { oc0 += lred[i]; oc1 += lred[64 + i]; }
        }
        __syncthreads();
    }
    u16* gr = g + (size_t)n * 8 * Kp;
    #pragma unroll
    for (int s = 0; s < S; ++s) {
        int k = t + 256 * s;
        if (k < Kp) {
            #pragma unroll
            for (int h = 0; h < 8; ++h) gr[h * Kp + k] = f2bf(acc[h][s]);
        }
    }
    if (t == 0) {
        oc0 *= 0.025f; oc1 *= 0.025f;   // 0.2 * (1/8)
        float a0 = cprev[n * 2], a1 = cprev[n * 2 + 1];
        cnext[n * 2]     = (a0 == 0.f) ? 0.f : ((a0 == 1.f) ? 1.f : oc0);
        cnext[n * 2 + 1] = (a1 == 1.f) ? 1.f : ((a1 == 0.f) ? 0.f : oc1);
    }
}

// ---------------- split-K MFMA GEMM: facc[z] += g @ Wt2^T slice; 128x64 tile ----------------
__global__ __launch_bounds__(256) void k_gemm_s(const u16* __restrict__ A,   // [M, KK]
                                                const u16* __restrict__ Bt,  // [NC, KK]
                                                float* __restrict__ facc,    // [split][M*NC]
                                                int M, int KK, int NC, int kchunk) {
    __shared__ u16 As[128 * 32];
    __shared__ u16 Bs[64 * 32];
    int tid = threadIdx.x;
    int wave = tid >> 6, lane = tid & 63;
    int bm = blockIdx.y * 128, bn = blockIdx.x * 64;
    int z = blockIdx.z;
    int kbeg = z * kchunk, kend = min(KK, kbeg + kchunk);
    int wm = (wave >> 1) * 64, wn = (wave & 1) * 32;
    int l16 = lane & 15, q = lane >> 4;
    f32x4 acc[4][2] = {};
    for (int k0 = kbeg; k0 < kend; k0 += 32) {
        #pragma unroll
        for (int it = 0; it < 2; ++it) {
            int seg = tid + it * 256;
            int row = seg >> 2, sq = seg & 3;
            uint4 va = {0u, 0u, 0u, 0u};
            int grow = bm + row;
            if (grow < M) va = *(const uint4*)(A + (size_t)grow * KK + k0 + sq * 8);
            *(uint4*)(As + row * 32 + ((sq ^ (row & 3)) * 8)) = va;
        }
        {
            int row = tid >> 2, sq = tid & 3;
            uint4 vb = *(const uint4*)(Bt + (size_t)(bn + row) * KK + k0 + sq * 8);
            *(uint4*)(Bs + row * 32 + ((sq ^ (row & 3)) * 8)) = vb;
        }
        __syncthreads();
        bf16x8 fa[4], fb[2];
        #pragma unroll
        for (int mi = 0; mi < 4; ++mi) {
            int row = wm + mi * 16 + l16;
            fa[mi] = *(const bf16x8*)(As + row * 32 + ((q ^ (row & 3)) * 8));
        }
        #pragma unroll
        for (int ni = 0; ni < 2; ++ni) {
            int col = wn + ni * 16 + l16;
            fb[ni] = *(const bf16x8*)(Bs + col * 32 + ((q ^ (col & 3)) * 8));
        }
        #pragma unroll
        for (int mi = 0; mi < 4; ++mi)
            #pragma unroll
            for (int ni = 0; ni < 2; ++ni)
                acc[mi][ni] = __builtin_amdgcn_mfma_f32_16x16x32_bf16(fa[mi], fb[ni], acc[mi][ni], 0, 0, 0);
        __syncthreads();
    }
    float* out = facc + (size_t)z * M * NC;
    #pragma unroll
    for (int mi = 0; mi < 4; ++mi) {
        int row0 = bm + wm + mi * 16 + q * 4;
        #pragma unroll
        for (int ni = 0; ni < 2; ++ni) {
            int col = bn + wn + ni * 16 + l16;
            #pragma unroll
            for (int r = 0; r < 4; ++r) {
                int row = row0 + r;
                if (row < M) out[(size_t)row * NC + col] = acc[mi][ni][r];
            }
        }
    }
}

// ---------------- reduce split partials + bias + selu ----------------
__global__ void k_fin(const float* __restrict__ facc, const float* __restrict__ bias,
                      float* __restrict__ fnext, int total, int cmask, int split, int MN) {
    int idx = blockIdx.x * 256 + threadIdx.x;
    if (idx >= total) return;
    float s = 0.f;
    for (int z = 0; z < split; ++z) s += facc[(size_t)z * MN + idx];
    fnext[idx] = selu_f(s * 0.125f + bias[idx & cmask]);
}

// ---------------- layer 4: coords only ----------------
__global__ void k_coords4(const float* __restrict__ wsum, const int* __restrict__ rowp,
                          const int* __restrict__ ssrc, const float* __restrict__ cprev,
                          float* __restrict__ outp) {
    int n = blockIdx.x * 256 + threadIdx.x;
    if (n >= N_NODES) return;
    int s0 = rowp[n], s1 = rowp[n + 1];
    float oc0 = 0.f, oc1 = 0.f;
    for (int s = s0; s < s1; ++s) {
        int src = ssrc[s];
        float w = wsum[s];
        oc0 += w * cprev[src * 2];
        oc1 += w * cprev[src * 2 + 1];
    }
    oc0 *= 0.2f * 0.125f;
    oc1 *= 0.2f * 0.125f;
    float a0 = cprev[n * 2], a1 = cprev[n * 2 + 1];
    outp[n * 2]     = (a0 == 0.f) ? 0.f : ((a0 == 1.f) ? 1.f : oc0);
    outp[n * 2 + 1] = (a1 == 1.f) ? 1.f : ((a1 == 0.f) ? 0.f : oc1);
}

extern "C" void kernel_launch(void* const* d_in, const int* in_sizes, int n_in,
                              void* d_out, int out_size, void* d_ws, size_t ws_size,
                              hipStream_t stream) {
    const float* data = (const float*)d_in[0];
    const int* ei = (const int*)d_in[1];
    const float* W0 = (const float*)d_in[2];
    const float* b0 = (const float*)d_in[3];
    int E = in_sizes[1] / 2;           // 40000
    int Esz = E + N_NODES;             // +self loops

    char* wp = (char*)d_ws;
    size_t off = 0;
    auto alloc = [&](size_t bytes) {
        void* p = wp + off;
        off += (bytes + 1023) & ~(size_t)1023;
        return p;
    };
    u16*   g     = (u16*)alloc((size_t)N_NODES * 8 * 576 * 2);
    u16*   Wt2   = (u16*)alloc((size_t)512 * 8 * 576 * 2);
    float* facc  = (float*)alloc((size_t)8 * N_NODES * 256 * 4);  // max split*M*C = 10.24M floats
    float* fA    = (float*)alloc((size_t)N_NODES * 512 * 4);
    float* fB    = (float*)alloc((size_t)N_NODES * 512 * 4);
    u16*   afb   = (u16*)alloc((size_t)N_NODES * 576 * 2);
    float* alpha = (float*)alloc((size_t)Esz * 8 * 4);
    float* wsum  = (float*)alloc((size_t)Esz * 4);
    float* es    = (float*)alloc((size_t)N_NODES * 8 * 4);
    float* ebd   = (float*)alloc((size_t)N_NODES * 8 * 4);
    float* fs    = (float*)alloc(516 * 8 * 4);
    float* fd    = (float*)alloc(516 * 8 * 4);
    float* c0    = (float*)alloc(N_NODES * 2 * 4);
    float* c1    = (float*)alloc(N_NODES * 2 * 4);
    float* c2    = (float*)alloc(N_NODES * 2 * 4);
    float* c3    = (float*)alloc(N_NODES * 2 * 4);
    int* cnt  = (int*)alloc(N_NODES * 2 * 4);  // cnt + cur adjacent, one memset
    int* cur  = cnt + N_NODES;
    int* rowp = (int*)alloc((N_NODES + 1) * 4);
    int* ssrc = (int*)alloc(Esz * 4);

    hipMemsetAsync(cnt, 0, N_NODES * 2 * 4, stream);
    int gE = (Esz + 255) / 256;
    k_count<<<gE, 256, 0, stream>>>(ei, cnt, E, Esz);
    k_scan<<<1, 256, 0, stream>>>(cnt, rowp, N_NODES);
    k_fill<<<gE, 256, 0, stream>>>(ei, rowp, cur, ssrc, E, Esz);
    k_feat0<<<N_NODES, 256, 0, stream>>>(data, W0, b0, fA, c0);

    struct LP { const float *W, *as, *ad, *bs; int K, C, split; };
    LP L[4] = {
        {(const float*)d_in[4],  (const float*)d_in[5],  (const float*)d_in[6],  (const float*)d_in[7],  258, 512, 4},
        {(const float*)d_in[8],  (const float*)d_in[9],  (const float*)d_in[10], (const float*)d_in[11], 516, 256, 8},
        {(const float*)d_in[12], (const float*)d_in[13], (const float*)d_in[14], (const float*)d_in[15], 262, 128, 8},
        {(const float*)d_in[16], (const float*)d_in[17], (const float*)d_in[18], (const float*)d_in[19], 136, 20, 1},
    };
    float* cbuf[4] = {c0, c1, c2, c3};
    float* featin[4] = {fA, fB, fA, fB};
    int FC[4] = {256, 512, 256, 128};

    for (int li = 0; li < 4; ++li) {
        LP& lp = L[li];
        const float* p[4] = {nullptr, nullptr, nullptr, nullptr};
        for (int j = 0; j <= li; ++j) p[j] = cbuf[li - j];
        int Kp = ((lp.K + 31) / 32) * 32;
        int KK = 8 * Kp;
        k_fold2<<<lp.K, 64, 0, stream>>>(lp.W, lp.as, lp.ad, fs, fd, lp.K, lp.C);
        k_ae<<<(N_NODES + 15) / 16, 256, 0, stream>>>(p[0], p[1], p[2], p[3], li + 1,
                                                      featin[li], FC[li], lp.K, Kp,
                                                      fs, fd, afb, es, ebd);
        if (li < 3)
            k_wtr2<<<dim3(lp.C / 32, KK / 32), 256, 0, stream>>>(lp.W, Wt2, lp.K, Kp, lp.C);
        k_alpha<<<(N_NODES + 3) / 4, 256, 0, stream>>>(es, ebd, rowp, ssrc, alpha, wsum);
        if (li < 3) {
            float* fnext = featin[li + 1];
            if (Kp <= 512)
                k_gather_g<2><<<N_NODES, 256, 0, stream>>>(afb, alpha, wsum, rowp, ssrc,
                                                           cbuf[li], g, cbuf[li + 1], Kp);
            else
                k_gather_g<3><<<N_NODES, 256, 0, stream>>>(afb, alpha, wsum, rowp, ssrc,
                                                           cbuf[li], g, cbuf[li + 1], Kp);
            int kchunk = KK / lp.split;   // L1: 2304/4=576, L2: 4352/8=544, L3: 2304/8=288
            k_gemm_s<<<dim3(lp.C / 64, (N_NODES + 127) / 128, lp.split), 256, 0, stream>>>(
                g, Wt2, facc, N_NODES, KK, lp.C, kchunk);
            int total = N_NODES * lp.C;
            k_fin<<<(total + 255) / 256, 256, 0, stream>>>(facc, lp.bs, fnext, total,
                                                           lp.C - 1, lp.split, total);
        } else {
            k_coords4<<<(N_NODES + 255) / 256, 256, 0, stream>>>(wsum, rowp, ssrc, cbuf[3],
                                                                 (float*)d_out);
        }
    }
}

// Round 6
// 452.259 us; speedup vs baseline: 1.2773x; 1.0261x over previous
//
#include <hip/hip_runtime.h>

#define N_NODES 5000
#define NH 8

typedef unsigned short u16;
typedef short bf16x8 __attribute__((ext_vector_type(8)));
typedef float f32x4 __attribute__((ext_vector_type(4)));

static __device__ __forceinline__ float selu_f(float x) {
    const float sc = 1.0507009873554805f;
    const float al = 1.6732632423543772f;
    return x > 0.f ? sc * x : sc * al * (__expf(x) - 1.f);
}

static __device__ __forceinline__ u16 f2bf(float x) {
    union { float f; unsigned u; } v; v.f = x;
    unsigned r = v.u + 0x7fff + ((v.u >> 16) & 1);
    return (u16)(r >> 16);
}

static __device__ __forceinline__ float bf2f(unsigned hi16) {
    union { unsigned u; float f; } v; v.u = hi16 << 16;
    return v.f;
}

// ---------------- CSR build ----------------
__global__ void k_count(const int* __restrict__ ei, int* cnt, int E, int Esz) {
    int e = blockIdx.x * 256 + threadIdx.x;
    if (e >= Esz) return;
    int dst = (e < E) ? ei[E + e] : (e - E);
    atomicAdd(&cnt[dst], 1);
}

__global__ void k_scan(const int* __restrict__ cnt, int* __restrict__ rowp, int n) {
    __shared__ int ps[256];
    int t = threadIdx.x;
    int per = (n + 255) / 256;
    int b = t * per;
    int s = 0;
    for (int i = 0; i < per; ++i) { int idx = b + i; if (idx < n) s += cnt[idx]; }
    ps[t] = s;
    __syncthreads();
    for (int off = 1; off < 256; off <<= 1) {
        int v = (t >= off) ? ps[t - off] : 0;
        __syncthreads();
        ps[t] += v;
        __syncthreads();
    }
    int run = (t == 0) ? 0 : ps[t - 1];
    for (int i = 0; i < per; ++i) {
        int idx = b + i;
        if (idx < n) { rowp[idx] = run; run += cnt[idx]; }
    }
    if (t == 255) rowp[n] = run;
}

__global__ void k_fill(const int* __restrict__ ei, const int* __restrict__ rowp,
                       int* cur, int* ssrc, int E, int Esz) {
    int e = blockIdx.x * 256 + threadIdx.x;
    if (e >= Esz) return;
    int src, dst;
    if (e < E) { src = ei[e]; dst = ei[E + e]; }
    else       { src = e - E; dst = src; }
    int pos = rowp[dst] + atomicAdd(&cur[dst], 1);
    ssrc[pos] = src;
}

// ---------------- feat0 = selu(data @ W0 + b0), and c0 = data[:, :2] ----------------
__global__ void k_feat0(const float* __restrict__ data, const float* __restrict__ W0,
                        const float* __restrict__ b0, float* __restrict__ f0,
                        float* __restrict__ c0) {
    int n = blockIdx.x;
    int t = threadIdx.x;   // 256
    __shared__ float d[10];
    if (t < 10) d[t] = data[n * 10 + t];
    __syncthreads();
    float acc = b0[t];
    #pragma unroll
    for (int k = 0; k < 10; ++k) acc += d[k] * W0[k * 256 + t];
    f0[(size_t)n * 256 + t] = selu_f(acc);
    if (t < 2) c0[n * 2 + t] = d[t];
}

// ---------------- fold: folded[k,h] = sum_c W[k, h*C+c]*a[h,c]  (wave per k, fp32) ----------------
__global__ void k_fold2(const float* __restrict__ W, const float* __restrict__ a_s,
                        const float* __restrict__ a_d, float* __restrict__ fs,
                        float* __restrict__ fd, int K, int C) {
    int k = blockIdx.x;
    int lane = threadIdx.x;   // 64
    float s[8] = {0.f,0.f,0.f,0.f,0.f,0.f,0.f,0.f};
    float d[8] = {0.f,0.f,0.f,0.f,0.f,0.f,0.f,0.f};
    const float* wr = W + (size_t)k * 8 * C;
    for (int c = lane; c < C; c += 64) {
        #pragma unroll
        for (int h = 0; h < 8; ++h) {
            float w = wr[h * C + c];
            s[h] += w * a_s[h * C + c];
            d[h] += w * a_d[h * C + c];
        }
    }
    #pragma unroll
    for (int off = 32; off >= 1; off >>= 1) {
        #pragma unroll
        for (int h = 0; h < 8; ++h) {
            s[h] += __shfl_xor(s[h], off);
            d[h] += __shfl_xor(d[h], off);
        }
    }
    if (lane == 0) {
        #pragma unroll
        for (int h = 0; h < 8; ++h) { fs[k * 8 + h] = s[h]; fd[k * 8 + h] = d[h]; }
    }
}

// ---------------- fused (split-reduce + bias + selu) + assemble + e ----------------
// feat element (n,cf): biasp ? selu(sum_z facc[z*MN + n*FC+cf]*0.125 + biasp[cf]) : fplain[n*FC+cf]
__global__ __launch_bounds__(256) void k_ae(const float* p0, const float* p1,
                                            const float* p2, const float* p3, int np,
                                            const float* __restrict__ fplain,
                                            const float* __restrict__ facc,
                                            const float* __restrict__ biasp,
                                            int split, int MN, int FC,
                                            int K, int Kp,
                                            const float* __restrict__ fs,
                                            const float* __restrict__ fd,
                                            u16* __restrict__ afb,
                                            float* __restrict__ es, float* __restrict__ ed) {
    __shared__ float As[16][66];
    __shared__ float Fs[64][16];
    int tid = threadIdx.x;
    int n0 = blockIdx.x * 16;
    int i = tid >> 4, j = tid & 15;
    float acc = 0.f;
    for (int k0 = 0; k0 < Kp; k0 += 64) {
        for (int idx = tid; idx < 1024; idx += 256) {
            int r = idx >> 6, cc = idx & 63;
            int c = k0 + cc, n = n0 + r;
            float v = 0.f;
            if (n < N_NODES && c < K) {
                if (c < 2 * np) {
                    const float* p = (c < 2) ? p0 : (c < 4) ? p1 : (c < 6) ? p2 : p3;
                    v = p[n * 2 + (c & 1)];
                } else {
                    int cf = c - 2 * np;
                    if (biasp) {
                        float sum = 0.f;
                        for (int z = 0; z < split; ++z)
                            sum += facc[(size_t)z * MN + (size_t)n * FC + cf];
                        v = selu_f(sum * 0.125f + biasp[cf]);
                    } else {
                        v = fplain[(size_t)n * FC + cf];
                    }
                }
            }
            As[r][cc] = v;
            if (n < N_NODES && c < Kp) afb[(size_t)n * Kp + c] = f2bf(v);
        }
        for (int idx = tid; idx < 1024; idx += 256) {
            int cc = idx >> 4, jj = idx & 15;
            int gk = k0 + cc;
            float v = 0.f;
            if (gk < K) v = (jj < 8) ? fs[gk * 8 + jj] : fd[gk * 8 + (jj - 8)];
            Fs[cc][jj] = v;
        }
        __syncthreads();
        #pragma unroll 8
        for (int cc = 0; cc < 64; ++cc) acc += As[i][cc] * Fs[cc][j];
        __syncthreads();
    }
    int n = n0 + i;
    if (n < N_NODES) {
        if (j < 8) es[n * 8 + j] = acc;
        else       ed[n * 8 + (j - 8)] = acc;
    }
}

// ---------------- W [K][8C] fp32 -> Wt2 [C][8*Kp] bf16: Wt2[c, h*Kp+k] = W[k, h*C+c] ----------------
__global__ __launch_bounds__(256) void k_wtr2(const float* __restrict__ W, u16* __restrict__ Wt2,
                                              int K, int Kp, int C) {
    __shared__ float tile[32][33];
    int c0 = blockIdx.x * 32;
    int j0 = blockIdx.y * 32;
    int h = j0 / Kp, k0 = j0 % Kp;
    int tid = threadIdx.x;
    for (int idx = tid; idx < 1024; idx += 256) {
        int kr = idx >> 5, cc = idx & 31;
        int gk = k0 + kr;
        tile[kr][cc] = (gk < K) ? W[(size_t)gk * (8 * C) + h * C + c0 + cc] : 0.f;
    }
    __syncthreads();
    int KK = 8 * Kp;
    for (int idx = tid; idx < 1024; idx += 256) {
        int cr = idx >> 5, kc = idx & 31;
        Wt2[(size_t)(c0 + cr) * KK + j0 + kc] = f2bf(tile[kc][cr]);
    }
}

// ---------------- fused softmax + gather + coords: block per dst node ----------------
// g[n, h*Kp+k] = sum_e alpha[e,h] * afb[src_e, k];  cnext from wsum
template <int S32>
__global__ __launch_bounds__(256) void k_gag(const float* __restrict__ es,
                            const float* __restrict__ ed,
                            const int* __restrict__ rowp, const int* __restrict__ ssrc,
                            const float* __restrict__ cprev, const u16* __restrict__ afb,
                            u16* __restrict__ g, float* __restrict__ cnext, int Kp) {
    __shared__ int   ls[128];
    __shared__ float la[128 * 8];
    __shared__ float lc0[128], lc1[128], lw[128];
    __shared__ float linv[8];
    int n = blockIdx.x, t = threadIdx.x;
    int s0 = rowp[n];
    int deg = rowp[n + 1] - s0;
    if (deg > 128) deg = 128;   // structurally impossible (mean deg 9)
    for (int i = t; i < deg; i += 256) {
        int src = ssrc[s0 + i];
        ls[i] = src;
        lc0[i] = cprev[src * 2];
        lc1[i] = cprev[src * 2 + 1];
    }
    __syncthreads();
    for (int i = t; i < deg * 8; i += 256) {
        int e = i >> 3, h = i & 7;
        float x = es[ls[e] * 8 + h] + ed[n * 8 + h];
        la[i] = x > 0.f ? x : 0.2f * x;
    }
    __syncthreads();
    if (t < 8) {
        float m = -1e30f;
        for (int e = 0; e < deg; ++e) m = fmaxf(m, la[e * 8 + t]);
        float s = 0.f;
        for (int e = 0; e < deg; ++e) {
            float v = __expf(la[e * 8 + t] - m);
            la[e * 8 + t] = v;
            s += v;
        }
        linv[t] = 1.f / s;
    }
    __syncthreads();
    for (int i = t; i < deg; i += 256) {
        float w = 0.f;
        #pragma unroll
        for (int h = 0; h < 8; ++h) w += la[i * 8 + h] * linv[h];
        lw[i] = w;
    }
    // ---- gather: un-normalized weights, scale at end ----
    int nW = Kp >> 1;   // u32 words per row
    float acc[8][2 * S32];
    #pragma unroll
    for (int h = 0; h < 8; ++h)
        #pragma unroll
        for (int s = 0; s < 2 * S32; ++s) acc[h][s] = 0.f;
    int e = 0;
    for (; e + 1 < deg; e += 2) {
        const unsigned* r0 = (const unsigned*)(afb + (size_t)ls[e] * Kp);
        const unsigned* r1 = (const unsigned*)(afb + (size_t)ls[e + 1] * Kp);
        unsigned v0[S32], v1[S32];
        #pragma unroll
        for (int s = 0; s < S32; ++s) {
            int w = t + 256 * s;
            v0[s] = (w < nW) ? r0[w] : 0u;
            v1[s] = (w < nW) ? r1[w] : 0u;
        }
        float a0[8], a1[8];
        #pragma unroll
        for (int h = 0; h < 8; ++h) { a0[h] = la[e * 8 + h]; a1[h] = la[(e + 1) * 8 + h]; }
        #pragma unroll
        for (int s = 0; s < S32; ++s) {
            float x0 = bf2f(v0[s] & 0xffff), y0 = bf2f(v0[s] >> 16);
            float x1 = bf2f(v1[s] & 0xffff), y1 = bf2f(v1[s] >> 16);
            #pragma unroll
            for (int h = 0; h < 8; ++h) {
                acc[h][2 * s]     += a0[h] * x0 + a1[h] * x1;
                acc[h][2 * s + 1] += a0[h] * y0 + a1[h] * y1;
            }
        }
    }
    if (e < deg) {
        const unsigned* r0 = (const unsigned*)(afb + (size_t)ls[e] * Kp);
        unsigned v0[S32];
        #pragma unroll
        for (int s = 0; s < S32; ++s) {
            int w = t + 256 * s;
            v0[s] = (w < nW) ? r0[w] : 0u;
        }
        float a0[8];
        #pragma unroll
        for (int h = 0; h < 8; ++h) a0[h] = la[e * 8 + h];
        #pragma unroll
        for (int s = 0; s < S32; ++s) {
            float x0 = bf2f(v0[s] & 0xffff), y0 = bf2f(v0[s] >> 16);
            #pragma unroll
            for (int h = 0; h < 8; ++h) {
                acc[h][2 * s]     += a0[h] * x0;
                acc[h][2 * s + 1] += a0[h] * y0;
            }
        }
    }
    unsigned* grw = (unsigned*)(g + (size_t)n * 8 * Kp);
    #pragma unroll
    for (int s = 0; s < S32; ++s) {
        int w = t + 256 * s;
        if (w < nW) {
            #pragma unroll
            for (int h = 0; h < 8; ++h) {
                float iv = linv[h];
                unsigned lo = f2bf(acc[h][2 * s] * iv);
                unsigned hi = f2bf(acc[h][2 * s + 1] * iv);
                grw[h * nW + w] = lo | (hi << 16);
            }
        }
    }
    __syncthreads();
    if (t == 0) {
        float oc0 = 0.f, oc1 = 0.f;
        for (int i = 0; i < deg; ++i) { oc0 += lw[i] * lc0[i]; oc1 += lw[i] * lc1[i]; }
        oc0 *= 0.025f; oc1 *= 0.025f;
        float a0 = cprev[n * 2], a1 = cprev[n * 2 + 1];
        cnext[n * 2]     = (a0 == 0.f) ? 0.f : ((a0 == 1.f) ? 1.f : oc0);
        cnext[n * 2 + 1] = (a1 == 1.f) ? 1.f : ((a1 == 0.f) ? 0.f : oc1);
    }
}

// ---------------- split-K MFMA GEMM, 128x128 tile: facc[z] = partial g @ Wt2^T ----------------
__global__ __launch_bounds__(256) void k_gemm_s(const u16* __restrict__ A,   // [M, KK]
                                                const u16* __restrict__ Bt,  // [NC, KK]
                                                float* __restrict__ facc,    // [split][M*NC]
                                                int M, int KK, int NC, int kchunk) {
    __shared__ u16 As[128 * 32];
    __shared__ u16 Bs[128 * 32];
    int tid = threadIdx.x;
    int wave = tid >> 6, lane = tid & 63;
    int bm = blockIdx.y * 128, bn = blockIdx.x * 128, z = blockIdx.z;
    int kbeg = z * kchunk, kend = min(KK, kbeg + kchunk);
    int wm = (wave >> 1) * 64, wn = (wave & 1) * 64;
    int l16 = lane & 15, q = lane >> 4;
    f32x4 acc[4][4] = {};
    for (int k0 = kbeg; k0 < kend; k0 += 32) {
        #pragma unroll
        for (int it = 0; it < 2; ++it) {
            int seg = tid + it * 256;
            int row = seg >> 2, sq = seg & 3;
            uint4 va = {0u, 0u, 0u, 0u};
            int grow = bm + row;
            if (grow < M) va = *(const uint4*)(A + (size_t)grow * KK + k0 + sq * 8);
            *(uint4*)(As + row * 32 + ((sq ^ (row & 3)) * 8)) = va;
            uint4 vb = *(const uint4*)(Bt + (size_t)(bn + row) * KK + k0 + sq * 8);
            *(uint4*)(Bs + row * 32 + ((sq ^ (row & 3)) * 8)) = vb;
        }
        __syncthreads();
        bf16x8 fa[4], fb[4];
        #pragma unroll
        for (int mi = 0; mi < 4; ++mi) {
            int row = wm + mi * 16 + l16;
            fa[mi] = *(const bf16x8*)(As + row * 32 + ((q ^ (row & 3)) * 8));
            int col = wn + mi * 16 + l16;
            fb[mi] = *(const bf16x8*)(Bs + col * 32 + ((q ^ (col & 3)) * 8));
        }
        #pragma unroll
        for (int mi = 0; mi < 4; ++mi)
            #pragma unroll
            for (int ni = 0; ni < 4; ++ni)
                acc[mi][ni] = __builtin_amdgcn_mfma_f32_16x16x32_bf16(fa[mi], fb[ni], acc[mi][ni], 0, 0, 0);
        __syncthreads();
    }
    float* out = facc + (size_t)z * M * NC;
    #pragma unroll
    for (int mi = 0; mi < 4; ++mi) {
        int row0 = bm + wm + mi * 16 + q * 4;
        #pragma unroll
        for (int ni = 0; ni < 4; ++ni) {
            int col = bn + wn + ni * 16 + l16;
            #pragma unroll
            for (int r = 0; r < 4; ++r) {
                int row = row0 + r;
                if (row < M) out[(size_t)row * NC + col] = acc[mi][ni][r];
            }
        }
    }
}

// ---------------- layer 4: fused softmax + coords -> output (wave per node) ----------------
__global__ void k_final(const float* __restrict__ es, const float* __restrict__ ed,
                        const int* __restrict__ rowp, const int* __restrict__ ssrc,
                        const float* __restrict__ cprev, float* __restrict__ outp) {
    int wid = (blockIdx.x * blockDim.x + threadIdx.x) >> 6;
    int lane = threadIdx.x & 63;
    if (wid >= N_NODES) return;
    int n = wid;
    int s0 = rowp[n], deg = rowp[n + 1] - s0;
    int h = lane & 7, ei = lane >> 3;
    float edh = ed[n * 8 + h];
    float m = -1e30f;
    for (int b = 0; b < deg; b += 8) {
        int e = b + ei;
        if (e < deg) {
            int src = ssrc[s0 + e];
            float x = es[src * 8 + h] + edh;
            x = x > 0.f ? x : 0.2f * x;
            m = fmaxf(m, x);
        }
    }
    m = fmaxf(m, __shfl_xor(m, 8));
    m = fmaxf(m, __shfl_xor(m, 16));
    m = fmaxf(m, __shfl_xor(m, 32));
    float ssum = 0.f;
    for (int b = 0; b < deg; b += 8) {
        int e = b + ei;
        if (e < deg) {
            int src = ssrc[s0 + e];
            float x = es[src * 8 + h] + edh;
            x = x > 0.f ? x : 0.2f * x;
            ssum += __expf(x - m);
        }
    }
    ssum += __shfl_xor(ssum, 8);
    ssum += __shfl_xor(ssum, 16);
    ssum += __shfl_xor(ssum, 32);
    float inv = 1.f / ssum;
    float oc0 = 0.f, oc1 = 0.f;
    for (int b = 0; b < deg; b += 8) {
        int e = b + ei;
        if (e < deg) {
            int src = ssrc[s0 + e];
            float x = es[src * 8 + h] + edh;
            x = x > 0.f ? x : 0.2f * x;
            float w = __expf(x - m) * inv;
            w += __shfl_xor(w, 1);
            w += __shfl_xor(w, 2);
            w += __shfl_xor(w, 4);
            if (h == 0) {
                oc0 += w * cprev[src * 2];
                oc1 += w * cprev[src * 2 + 1];
            }
        }
    }
    oc0 += __shfl_xor(oc0, 8);  oc1 += __shfl_xor(oc1, 8);
    oc0 += __shfl_xor(oc0, 16); oc1 += __shfl_xor(oc1, 16);
    oc0 += __shfl_xor(oc0, 32); oc1 += __shfl_xor(oc1, 32);
    if (lane == 0) {
        oc0 *= 0.025f; oc1 *= 0.025f;
        float a0 = cprev[n * 2], a1 = cprev[n * 2 + 1];
        outp[n * 2]     = (a0 == 0.f) ? 0.f : ((a0 == 1.f) ? 1.f : oc0);
        outp[n * 2 + 1] = (a1 == 1.f) ? 1.f : ((a1 == 0.f) ? 0.f : oc1);
    }
}

extern "C" void kernel_launch(void* const* d_in, const int* in_sizes, int n_in,
                              void* d_out, int out_size, void* d_ws, size_t ws_size,
                              hipStream_t stream) {
    const float* data = (const float*)d_in[0];
    const int* ei = (const int*)d_in[1];
    const float* W0 = (const float*)d_in[2];
    const float* b0 = (const float*)d_in[3];
    int E = in_sizes[1] / 2;
    int Esz = E + N_NODES;

    char* wp = (char*)d_ws;
    size_t off = 0;
    auto alloc = [&](size_t bytes) {
        void* p = wp + off;
        off += (bytes + 1023) & ~(size_t)1023;
        return p;
    };
    u16*   g     = (u16*)alloc((size_t)N_NODES * 8 * 576 * 2);
    u16*   Wt2   = (u16*)alloc((size_t)512 * 8 * 576 * 2);
    float* facc  = (float*)alloc((size_t)N_NODES * 2048 * 4);
    float* fA    = (float*)alloc((size_t)N_NODES * 256 * 4);
    u16*   afb   = (u16*)alloc((size_t)N_NODES * 576 * 2);
    float* es    = (float*)alloc((size_t)N_NODES * 8 * 4);
    float* ebd   = (float*)alloc((size_t)N_NODES * 8 * 4);
    float* fs    = (float*)alloc(516 * 8 * 4);
    float* fd    = (float*)alloc(516 * 8 * 4);
    float* c0    = (float*)alloc(N_NODES * 2 * 4);
    float* c1    = (float*)alloc(N_NODES * 2 * 4);
    float* c2    = (float*)alloc(N_NODES * 2 * 4);
    float* c3    = (float*)alloc(N_NODES * 2 * 4);
    int* cnt  = (int*)alloc(N_NODES * 2 * 4);
    int* cur  = cnt + N_NODES;
    int* rowp = (int*)alloc((N_NODES + 1) * 4);
    int* ssrc = (int*)alloc(Esz * 4);

    hipMemsetAsync(cnt, 0, N_NODES * 2 * 4, stream);
    int gE = (Esz + 255) / 256;
    k_count<<<gE, 256, 0, stream>>>(ei, cnt, E, Esz);
    k_scan<<<1, 256, 0, stream>>>(cnt, rowp, N_NODES);
    k_fill<<<gE, 256, 0, stream>>>(ei, rowp, cur, ssrc, E, Esz);
    k_feat0<<<N_NODES, 256, 0, stream>>>(data, W0, b0, fA, c0);

    struct LP { const float *W, *as, *ad, *bs; int K, C, split; };
    LP L[4] = {
        {(const float*)d_in[4],  (const float*)d_in[5],  (const float*)d_in[6],  (const float*)d_in[7],  258, 512, 4},
        {(const float*)d_in[8],  (const float*)d_in[9],  (const float*)d_in[10], (const float*)d_in[11], 516, 256, 8},
        {(const float*)d_in[12], (const float*)d_in[13], (const float*)d_in[14], (const float*)d_in[15], 262, 128, 8},
        {(const float*)d_in[16], (const float*)d_in[17], (const float*)d_in[18], (const float*)d_in[19], 136, 20, 1},
    };
    float* cbuf[4] = {c0, c1, c2, c3};
    int FC[4] = {256, 512, 256, 128};   // feat width consumed by layer li

    for (int li = 0; li < 4; ++li) {
        LP& lp = L[li];
        const float* p[4] = {nullptr, nullptr, nullptr, nullptr};
        for (int j = 0; j <= li; ++j) p[j] = cbuf[li - j];
        int Kp = ((lp.K + 31) / 32) * 32;
        int KK = 8 * Kp;
        const float* biasp = (li == 0) ? nullptr : L[li - 1].bs;
        int splitp = (li == 0) ? 1 : L[li - 1].split;
        int MNp = N_NODES * FC[li];

        k_fold2<<<lp.K, 64, 0, stream>>>(lp.W, lp.as, lp.ad, fs, fd, lp.K, lp.C);
        k_ae<<<(N_NODES + 15) / 16, 256, 0, stream>>>(p[0], p[1], p[2], p[3], li + 1,
                                                      fA, facc, biasp, splitp, MNp, FC[li],
                                                      lp.K, Kp, fs, fd, afb, es, ebd);
        if (li < 3) {
            k_wtr2<<<dim3(lp.C / 32, KK / 32), 256, 0, stream>>>(lp.W, Wt2, lp.K, Kp, lp.C);
            if ((Kp >> 1) <= 256)
                k_gag<1><<<N_NODES, 256, 0, stream>>>(es, ebd, rowp, ssrc, cbuf[li], afb,
                                                      g, cbuf[li + 1], Kp);
            else
                k_gag<2><<<N_NODES, 256, 0, stream>>>(es, ebd, rowp, ssrc, cbuf[li], afb,
                                                      g, cbuf[li + 1], Kp);
            k_gemm_s<<<dim3(lp.C / 128, (N_NODES + 127) / 128, lp.split), 256, 0, stream>>>(
                g, Wt2, facc, N_NODES, KK, lp.C, KK / lp.split);
        } else {
            k_final<<<(N_NODES + 3) / 4, 256, 0, stream>>>(es, ebd, rowp, ssrc, cbuf[3],
                                                           (float*)d_out);
        }
    }
}

// Round 7
// 381.455 us; speedup vs baseline: 1.5144x; 1.1856x over previous
//
#include <hip/hip_runtime.h>

#define N_NODES 5000
#define NH 8

typedef unsigned short u16;
typedef short bf16x8 __attribute__((ext_vector_type(8)));
typedef float f32x4 __attribute__((ext_vector_type(4)));

static __device__ __forceinline__ float selu_f(float x) {
    const float sc = 1.0507009873554805f;
    const float al = 1.6732632423543772f;
    return x > 0.f ? sc * x : sc * al * (__expf(x) - 1.f);
}

static __device__ __forceinline__ u16 f2bf(float x) {
    union { float f; unsigned u; } v; v.f = x;
    unsigned r = v.u + 0x7fff + ((v.u >> 16) & 1);
    return (u16)(r >> 16);
}

static __device__ __forceinline__ float bf2f(unsigned hi16) {
    union { unsigned u; float f; } v; v.u = hi16 << 16;
    return v.f;
}

// ---------------- CSR build ----------------
__global__ void k_count(const int* __restrict__ ei, int* cnt, int E, int Esz) {
    int e = blockIdx.x * 256 + threadIdx.x;
    if (e >= Esz) return;
    int dst = (e < E) ? ei[E + e] : (e - E);
    atomicAdd(&cnt[dst], 1);
}

__global__ void k_scan(const int* __restrict__ cnt, int* __restrict__ rowp, int n) {
    __shared__ int ps[256];
    int t = threadIdx.x;
    int per = (n + 255) / 256;
    int b = t * per;
    int s = 0;
    for (int i = 0; i < per; ++i) { int idx = b + i; if (idx < n) s += cnt[idx]; }
    ps[t] = s;
    __syncthreads();
    for (int off = 1; off < 256; off <<= 1) {
        int v = (t >= off) ? ps[t - off] : 0;
        __syncthreads();
        ps[t] += v;
        __syncthreads();
    }
    int run = (t == 0) ? 0 : ps[t - 1];
    for (int i = 0; i < per; ++i) {
        int idx = b + i;
        if (idx < n) { rowp[idx] = run; run += cnt[idx]; }
    }
    if (t == 255) rowp[n] = run;
}

__global__ void k_fill(const int* __restrict__ ei, const int* __restrict__ rowp,
                       int* cur, int* ssrc, int E, int Esz) {
    int e = blockIdx.x * 256 + threadIdx.x;
    if (e >= Esz) return;
    int src, dst;
    if (e < E) { src = ei[e]; dst = ei[E + e]; }
    else       { src = e - E; dst = src; }
    int pos = rowp[dst] + atomicAdd(&cur[dst], 1);
    ssrc[pos] = src;
}

// ---------------- feat0 = selu(data @ W0 + b0), and c0 = data[:, :2] ----------------
__global__ void k_feat0(const float* __restrict__ data, const float* __restrict__ W0,
                        const float* __restrict__ b0, float* __restrict__ f0,
                        float* __restrict__ c0) {
    int n = blockIdx.x;
    int t = threadIdx.x;   // 256
    __shared__ float d[10];
    if (t < 10) d[t] = data[n * 10 + t];
    __syncthreads();
    float acc = b0[t];
    #pragma unroll
    for (int k = 0; k < 10; ++k) acc += d[k] * W0[k * 256 + t];
    f0[(size_t)n * 256 + t] = selu_f(acc);
    if (t < 2) c0[n * 2 + t] = d[t];
}

// ---------------- foldall: all 4 layers; folded[li][k][h] = sum_c W[k,h*C+c]*a[h,c] ----------------
__global__ void k_foldall(const float* W1, const float* W2, const float* W3, const float* W4,
                          const float* s1, const float* s2, const float* s3, const float* s4,
                          const float* d1, const float* d2, const float* d3, const float* d4,
                          float* __restrict__ fsAll, float* __restrict__ fdAll) {
    const int Ks[4] = {258, 516, 262, 136};
    const int Cs[4] = {512, 256, 128, 20};
    int li = blockIdx.y;
    int k = blockIdx.x;
    if (k >= Ks[li]) return;
    const float* W  = (li == 0) ? W1 : (li == 1) ? W2 : (li == 2) ? W3 : W4;
    const float* as = (li == 0) ? s1 : (li == 1) ? s2 : (li == 2) ? s3 : s4;
    const float* ad = (li == 0) ? d1 : (li == 1) ? d2 : (li == 2) ? d3 : d4;
    int C = Cs[li];
    int lane = threadIdx.x;   // 64
    float s[8] = {0.f,0.f,0.f,0.f,0.f,0.f,0.f,0.f};
    float d[8] = {0.f,0.f,0.f,0.f,0.f,0.f,0.f,0.f};
    const float* wr = W + (size_t)k * 8 * C;
    for (int c = lane; c < C; c += 64) {
        #pragma unroll
        for (int h = 0; h < 8; ++h) {
            float w = wr[h * C + c];
            s[h] += w * as[h * C + c];
            d[h] += w * ad[h * C + c];
        }
    }
    #pragma unroll
    for (int off = 32; off >= 1; off >>= 1) {
        #pragma unroll
        for (int h = 0; h < 8; ++h) {
            s[h] += __shfl_xor(s[h], off);
            d[h] += __shfl_xor(d[h], off);
        }
    }
    if (lane == 0) {
        float* fo = fsAll + (size_t)li * 516 * 8 + k * 8;
        float* go = fdAll + (size_t)li * 516 * 8 + k * 8;
        #pragma unroll
        for (int h = 0; h < 8; ++h) { fo[h] = s[h]; go[h] = d[h]; }
    }
}

// ---------------- wtrall: all 3 layers; Wt2[c, h*Kp+k] = W[k, h*C+c] (bf16) ----------------
__global__ __launch_bounds__(256) void k_wtrall(const float* W1, const float* W2, const float* W3,
                                                u16* T1, u16* T2, u16* T3) {
    const int Ks[3] = {258, 516, 262};
    const int Cs[3] = {512, 256, 128};
    const int Kps[3] = {288, 544, 288};
    int li = blockIdx.z;
    int C = Cs[li], K = Ks[li], Kp = Kps[li], KK = 8 * Kp;
    int c0 = blockIdx.x * 32;
    int j0 = blockIdx.y * 32;
    if (c0 >= C || j0 >= KK) return;
    const float* W = (li == 0) ? W1 : (li == 1) ? W2 : W3;
    u16* Wt2 = (li == 0) ? T1 : (li == 1) ? T2 : T3;
    __shared__ float tile[32][33];
    int h = j0 / Kp, k0 = j0 % Kp;
    int tid = threadIdx.x;
    for (int idx = tid; idx < 1024; idx += 256) {
        int kr = idx >> 5, cc = idx & 31;
        int gk = k0 + kr;
        tile[kr][cc] = (gk < K) ? W[(size_t)gk * (8 * C) + h * C + c0 + cc] : 0.f;
    }
    __syncthreads();
    for (int idx = tid; idx < 1024; idx += 256) {
        int cr = idx >> 5, kc = idx & 31;
        Wt2[(size_t)(c0 + cr) * KK + j0 + kc] = f2bf(tile[kc][cr]);
    }
}

// ---------------- k_mf: block per node. feat = split-reduce+bias+selu (or fplain);
// writes afb bf16 row; computes es/ed = sum_c af[n,c]*{fs,fd}[c,:] in fp32 ----------------
__global__ __launch_bounds__(256) void k_mf(const float* p0, const float* p1,
                                            const float* p2, const float* p3, int np,
                                            const float* __restrict__ fplain,
                                            const float* __restrict__ facc,
                                            const float* __restrict__ biasp,
                                            int split, int MN, int FC, int K, int Kp,
                                            const float* __restrict__ fs,
                                            const float* __restrict__ fd,
                                            u16* __restrict__ afb,
                                            float* __restrict__ es, float* __restrict__ ed) {
    int n = blockIdx.x, t = threadIdx.x;
    float pes[8] = {0.f,0.f,0.f,0.f,0.f,0.f,0.f,0.f};
    float ped[8] = {0.f,0.f,0.f,0.f,0.f,0.f,0.f,0.f};
    u16* rowb = afb + (size_t)n * Kp;
    for (int cf = t; cf < FC; cf += 256) {
        float v;
        if (biasp) {
            float s = 0.f;
            for (int z = 0; z < split; ++z)
                s += facc[(size_t)z * MN + (size_t)n * FC + cf];
            v = selu_f(s * 0.125f + biasp[cf]);
        } else {
            v = fplain[(size_t)n * FC + cf];
        }
        int c = 2 * np + cf;
        rowb[c] = f2bf(v);
        const float* fsr = fs + c * 8;
        const float* fdr = fd + c * 8;
        #pragma unroll
        for (int h = 0; h < 8; ++h) { pes[h] += v * fsr[h]; ped[h] += v * fdr[h]; }
    }
    if (t < 2 * np) {
        const float* p = (t < 2) ? p0 : (t < 4) ? p1 : (t < 6) ? p2 : p3;
        float v = p[n * 2 + (t & 1)];
        rowb[t] = f2bf(v);
        #pragma unroll
        for (int h = 0; h < 8; ++h) { pes[h] += v * fs[t * 8 + h]; ped[h] += v * fd[t * 8 + h]; }
    }
    for (int c = K + t; c < Kp; c += 256) rowb[c] = 0;
    #pragma unroll
    for (int off = 32; off >= 1; off >>= 1) {
        #pragma unroll
        for (int h = 0; h < 8; ++h) {
            pes[h] += __shfl_xor(pes[h], off);
            ped[h] += __shfl_xor(ped[h], off);
        }
    }
    __shared__ float red[4][16];
    int wv = t >> 6, ln = t & 63;
    if (ln == 0) {
        #pragma unroll
        for (int h = 0; h < 8; ++h) { red[wv][h] = pes[h]; red[wv][8 + h] = ped[h]; }
    }
    __syncthreads();
    if (t < 16) {
        float s = red[0][t] + red[1][t] + red[2][t] + red[3][t];
        if (t < 8) es[n * 8 + t] = s;
        else       ed[n * 8 + (t - 8)] = s;
    }
}

// ---------------- fused softmax + gather + coords: block per dst node ----------------
template <int S32>
__global__ __launch_bounds__(256) void k_gag(const float* __restrict__ es,
                            const float* __restrict__ ed,
                            const int* __restrict__ rowp, const int* __restrict__ ssrc,
                            const float* __restrict__ cprev, const u16* __restrict__ afb,
                            u16* __restrict__ g, float* __restrict__ cnext, int Kp) {
    __shared__ int   ls[128];
    __shared__ float la[128 * 8];
    __shared__ float lc0[128], lc1[128], lw[128];
    __shared__ float linv[8];
    int n = blockIdx.x, t = threadIdx.x;
    int s0 = rowp[n];
    int deg = rowp[n + 1] - s0;
    if (deg > 128) deg = 128;
    for (int i = t; i < deg; i += 256) {
        int src = ssrc[s0 + i];
        ls[i] = src;
        lc0[i] = cprev[src * 2];
        lc1[i] = cprev[src * 2 + 1];
    }
    __syncthreads();
    for (int i = t; i < deg * 8; i += 256) {
        int e = i >> 3, h = i & 7;
        float x = es[ls[e] * 8 + h] + ed[n * 8 + h];
        la[i] = x > 0.f ? x : 0.2f * x;
    }
    __syncthreads();
    if (t < 8) {
        float m = -1e30f;
        for (int e = 0; e < deg; ++e) m = fmaxf(m, la[e * 8 + t]);
        float s = 0.f;
        for (int e = 0; e < deg; ++e) {
            float v = __expf(la[e * 8 + t] - m);
            la[e * 8 + t] = v;
            s += v;
        }
        linv[t] = 1.f / s;
    }
    __syncthreads();
    for (int i = t; i < deg; i += 256) {
        float w = 0.f;
        #pragma unroll
        for (int h = 0; h < 8; ++h) w += la[i * 8 + h] * linv[h];
        lw[i] = w;
    }
    int nW = Kp >> 1;
    float acc[8][2 * S32];
    #pragma unroll
    for (int h = 0; h < 8; ++h)
        #pragma unroll
        for (int s = 0; s < 2 * S32; ++s) acc[h][s] = 0.f;
    int e = 0;
    for (; e + 1 < deg; e += 2) {
        const unsigned* r0 = (const unsigned*)(afb + (size_t)ls[e] * Kp);
        const unsigned* r1 = (const unsigned*)(afb + (size_t)ls[e + 1] * Kp);
        unsigned v0[S32], v1[S32];
        #pragma unroll
        for (int s = 0; s < S32; ++s) {
            int w = t + 256 * s;
            v0[s] = (w < nW) ? r0[w] : 0u;
            v1[s] = (w < nW) ? r1[w] : 0u;
        }
        float a0[8], a1[8];
        #pragma unroll
        for (int h = 0; h < 8; ++h) { a0[h] = la[e * 8 + h]; a1[h] = la[(e + 1) * 8 + h]; }
        #pragma unroll
        for (int s = 0; s < S32; ++s) {
            float x0 = bf2f(v0[s] & 0xffff), y0 = bf2f(v0[s] >> 16);
            float x1 = bf2f(v1[s] & 0xffff), y1 = bf2f(v1[s] >> 16);
            #pragma unroll
            for (int h = 0; h < 8; ++h) {
                acc[h][2 * s]     += a0[h] * x0 + a1[h] * x1;
                acc[h][2 * s + 1] += a0[h] * y0 + a1[h] * y1;
            }
        }
    }
    if (e < deg) {
        const unsigned* r0 = (const unsigned*)(afb + (size_t)ls[e] * Kp);
        unsigned v0[S32];
        #pragma unroll
        for (int s = 0; s < S32; ++s) {
            int w = t + 256 * s;
            v0[s] = (w < nW) ? r0[w] : 0u;
        }
        float a0[8];
        #pragma unroll
        for (int h = 0; h < 8; ++h) a0[h] = la[e * 8 + h];
        #pragma unroll
        for (int s = 0; s < S32; ++s) {
            float x0 = bf2f(v0[s] & 0xffff), y0 = bf2f(v0[s] >> 16);
            #pragma unroll
            for (int h = 0; h < 8; ++h) {
                acc[h][2 * s]     += a0[h] * x0;
                acc[h][2 * s + 1] += a0[h] * y0;
            }
        }
    }
    unsigned* grw = (unsigned*)(g + (size_t)n * 8 * Kp);
    #pragma unroll
    for (int s = 0; s < S32; ++s) {
        int w = t + 256 * s;
        if (w < nW) {
            #pragma unroll
            for (int h = 0; h < 8; ++h) {
                float iv = linv[h];
                unsigned lo = f2bf(acc[h][2 * s] * iv);
                unsigned hi = f2bf(acc[h][2 * s + 1] * iv);
                grw[h * nW + w] = lo | (hi << 16);
            }
        }
    }
    __syncthreads();
    if (t == 0) {
        float oc0 = 0.f, oc1 = 0.f;
        for (int i = 0; i < deg; ++i) { oc0 += lw[i] * lc0[i]; oc1 += lw[i] * lc1[i]; }
        oc0 *= 0.025f; oc1 *= 0.025f;
        float a0 = cprev[n * 2], a1 = cprev[n * 2 + 1];
        cnext[n * 2]     = (a0 == 0.f) ? 0.f : ((a0 == 1.f) ? 1.f : oc0);
        cnext[n * 2 + 1] = (a1 == 1.f) ? 1.f : ((a1 == 0.f) ? 0.f : oc1);
    }
}

// ---------------- split-K MFMA GEMM, 128x128 tile: facc[z] = partial g @ Wt2^T ----------------
__global__ __launch_bounds__(256) void k_gemm_s(const u16* __restrict__ A,   // [M, KK]
                                                const u16* __restrict__ Bt,  // [NC, KK]
                                                float* __restrict__ facc,    // [split][M*NC]
                                                int M, int KK, int NC, int kchunk) {
    __shared__ u16 As[128 * 32];
    __shared__ u16 Bs[128 * 32];
    int tid = threadIdx.x;
    int wave = tid >> 6, lane = tid & 63;
    int bm = blockIdx.y * 128, bn = blockIdx.x * 128, z = blockIdx.z;
    int kbeg = z * kchunk, kend = min(KK, kbeg + kchunk);
    int wm = (wave >> 1) * 64, wn = (wave & 1) * 64;
    int l16 = lane & 15, q = lane >> 4;
    f32x4 acc[4][4] = {};
    for (int k0 = kbeg; k0 < kend; k0 += 32) {
        #pragma unroll
        for (int it = 0; it < 2; ++it) {
            int seg = tid + it * 256;
            int row = seg >> 2, sq = seg & 3;
            uint4 va = {0u, 0u, 0u, 0u};
            int grow = bm + row;
            if (grow < M) va = *(const uint4*)(A + (size_t)grow * KK + k0 + sq * 8);
            *(uint4*)(As + row * 32 + ((sq ^ (row & 3)) * 8)) = va;
            uint4 vb = *(const uint4*)(Bt + (size_t)(bn + row) * KK + k0 + sq * 8);
            *(uint4*)(Bs + row * 32 + ((sq ^ (row & 3)) * 8)) = vb;
        }
        __syncthreads();
        bf16x8 fa[4], fb[4];
        #pragma unroll
        for (int mi = 0; mi < 4; ++mi) {
            int row = wm + mi * 16 + l16;
            fa[mi] = *(const bf16x8*)(As + row * 32 + ((q ^ (row & 3)) * 8));
            int col = wn + mi * 16 + l16;
            fb[mi] = *(const bf16x8*)(Bs + col * 32 + ((q ^ (col & 3)) * 8));
        }
        #pragma unroll
        for (int mi = 0; mi < 4; ++mi)
            #pragma unroll
            for (int ni = 0; ni < 4; ++ni)
                acc[mi][ni] = __builtin_amdgcn_mfma_f32_16x16x32_bf16(fa[mi], fb[ni], acc[mi][ni], 0, 0, 0);
        __syncthreads();
    }
    float* out = facc + (size_t)z * M * NC;
    #pragma unroll
    for (int mi = 0; mi < 4; ++mi) {
        int row0 = bm + wm + mi * 16 + q * 4;
        #pragma unroll
        for (int ni = 0; ni < 4; ++ni) {
            int col = bn + wn + ni * 16 + l16;
            #pragma unroll
            for (int r = 0; r < 4; ++r) {
                int row = row0 + r;
                if (row < M) out[(size_t)row * NC + col] = acc[mi][ni][r];
            }
        }
    }
}

// ---------------- layer 4: fused softmax + coords -> output (wave per node) ----------------
__global__ void k_final(const float* __restrict__ es, const float* __restrict__ ed,
                        const int* __restrict__ rowp, const int* __restrict__ ssrc,
                        const float* __restrict__ cprev, float* __restrict__ outp) {
    int wid = (blockIdx.x * blockDim.x + threadIdx.x) >> 6;
    int lane = threadIdx.x & 63;
    if (wid >= N_NODES) return;
    int n = wid;
    int s0 = rowp[n], deg = rowp[n + 1] - s0;
    int h = lane & 7, ei = lane >> 3;
    float edh = ed[n * 8 + h];
    float m = -1e30f;
    for (int b = 0; b < deg; b += 8) {
        int e = b + ei;
        if (e < deg) {
            int src = ssrc[s0 + e];
            float x = es[src * 8 + h] + edh;
            x = x > 0.f ? x : 0.2f * x;
            m = fmaxf(m, x);
        }
    }
    m = fmaxf(m, __shfl_xor(m, 8));
    m = fmaxf(m, __shfl_xor(m, 16));
    m = fmaxf(m, __shfl_xor(m, 32));
    float ssum = 0.f;
    for (int b = 0; b < deg; b += 8) {
        int e = b + ei;
        if (e < deg) {
            int src = ssrc[s0 + e];
            float x = es[src * 8 + h] + edh;
            x = x > 0.f ? x : 0.2f * x;
            ssum += __expf(x - m);
        }
    }
    ssum += __shfl_xor(ssum, 8);
    ssum += __shfl_xor(ssum, 16);
    ssum += __shfl_xor(ssum, 32);
    float inv = 1.f / ssum;
    float oc0 = 0.f, oc1 = 0.f;
    for (int b = 0; b < deg; b += 8) {
        int e = b + ei;
        if (e < deg) {
            int src = ssrc[s0 + e];
            float x = es[src * 8 + h] + edh;
            x = x > 0.f ? x : 0.2f * x;
            float w = __expf(x - m) * inv;
            w += __shfl_xor(w, 1);
            w += __shfl_xor(w, 2);
            w += __shfl_xor(w, 4);
            if (h == 0) {
                oc0 += w * cprev[src * 2];
                oc1 += w * cprev[src * 2 + 1];
            }
        }
    }
    oc0 += __shfl_xor(oc0, 8);  oc1 += __shfl_xor(oc1, 8);
    oc0 += __shfl_xor(oc0, 16); oc1 += __shfl_xor(oc1, 16);
    oc0 += __shfl_xor(oc0, 32); oc1 += __shfl_xor(oc1, 32);
    if (lane == 0) {
        oc0 *= 0.025f; oc1 *= 0.025f;
        float a0 = cprev[n * 2], a1 = cprev[n * 2 + 1];
        outp[n * 2]     = (a0 == 0.f) ? 0.f : ((a0 == 1.f) ? 1.f : oc0);
        outp[n * 2 + 1] = (a1 == 1.f) ? 1.f : ((a1 == 0.f) ? 0.f : oc1);
    }
}

extern "C" void kernel_launch(void* const* d_in, const int* in_sizes, int n_in,
                              void* d_out, int out_size, void* d_ws, size_t ws_size,
                              hipStream_t stream) {
    const float* data = (const float*)d_in[0];
    const int* ei = (const int*)d_in[1];
    const float* W0 = (const float*)d_in[2];
    const float* b0 = (const float*)d_in[3];
    int E = in_sizes[1] / 2;
    int Esz = E + N_NODES;

    char* wp = (char*)d_ws;
    size_t off = 0;
    auto alloc = [&](size_t bytes) {
        void* p = wp + off;
        off += (bytes + 1023) & ~(size_t)1023;
        return p;
    };
    u16*   g     = (u16*)alloc((size_t)N_NODES * 8 * 576 * 2);
    u16*   T1    = (u16*)alloc((size_t)512 * 8 * 288 * 2);
    u16*   T2    = (u16*)alloc((size_t)256 * 8 * 544 * 2);
    u16*   T3    = (u16*)alloc((size_t)128 * 8 * 288 * 2);
    float* facc  = (float*)alloc((size_t)N_NODES * 2048 * 4);
    float* fA    = (float*)alloc((size_t)N_NODES * 256 * 4);
    u16*   afb   = (u16*)alloc((size_t)N_NODES * 576 * 2);
    float* es    = (float*)alloc((size_t)N_NODES * 8 * 4);
    float* ebd   = (float*)alloc((size_t)N_NODES * 8 * 4);
    float* fsAll = (float*)alloc((size_t)4 * 516 * 8 * 4);
    float* fdAll = (float*)alloc((size_t)4 * 516 * 8 * 4);
    float* c0    = (float*)alloc(N_NODES * 2 * 4);
    float* c1    = (float*)alloc(N_NODES * 2 * 4);
    float* c2    = (float*)alloc(N_NODES * 2 * 4);
    float* c3    = (float*)alloc(N_NODES * 2 * 4);
    int* cnt  = (int*)alloc(N_NODES * 2 * 4);
    int* cur  = cnt + N_NODES;
    int* rowp = (int*)alloc((N_NODES + 1) * 4);
    int* ssrc = (int*)alloc(Esz * 4);

    hipMemsetAsync(cnt, 0, N_NODES * 2 * 4, stream);
    int gE = (Esz + 255) / 256;
    k_count<<<gE, 256, 0, stream>>>(ei, cnt, E, Esz);
    k_scan<<<1, 256, 0, stream>>>(cnt, rowp, N_NODES);
    k_fill<<<gE, 256, 0, stream>>>(ei, rowp, cur, ssrc, E, Esz);
    k_feat0<<<N_NODES, 256, 0, stream>>>(data, W0, b0, fA, c0);

    struct LP { const float *W, *as, *ad, *bs; int K, C, split; };
    LP L[4] = {
        {(const float*)d_in[4],  (const float*)d_in[5],  (const float*)d_in[6],  (const float*)d_in[7],  258, 512, 4},
        {(const float*)d_in[8],  (const float*)d_in[9],  (const float*)d_in[10], (const float*)d_in[11], 516, 256, 8},
        {(const float*)d_in[12], (const float*)d_in[13], (const float*)d_in[14], (const float*)d_in[15], 262, 128, 8},
        {(const float*)d_in[16], (const float*)d_in[17], (const float*)d_in[18], (const float*)d_in[19], 136, 20, 1},
    };
    k_foldall<<<dim3(516, 4), 64, 0, stream>>>(L[0].W, L[1].W, L[2].W, L[3].W,
                                               L[0].as, L[1].as, L[2].as, L[3].as,
                                               L[0].ad, L[1].ad, L[2].ad, L[3].ad,
                                               fsAll, fdAll);
    k_wtrall<<<dim3(16, 136, 3), 256, 0, stream>>>(L[0].W, L[1].W, L[2].W, T1, T2, T3);

    float* cbuf[4] = {c0, c1, c2, c3};
    u16* Tb[3] = {T1, T2, T3};
    int FC[4] = {256, 512, 256, 128};   // feat width consumed by layer li

    for (int li = 0; li < 4; ++li) {
        LP& lp = L[li];
        const float* p[4] = {nullptr, nullptr, nullptr, nullptr};
        for (int j = 0; j <= li; ++j) p[j] = cbuf[li - j];
        int Kp = ((lp.K + 31) / 32) * 32;
        int KK = 8 * Kp;
        const float* biasp = (li == 0) ? nullptr : L[li - 1].bs;
        int splitp = (li == 0) ? 1 : L[li - 1].split;
        int MNp = N_NODES * FC[li];
        const float* fs = fsAll + (size_t)li * 516 * 8;
        const float* fd = fdAll + (size_t)li * 516 * 8;

        k_mf<<<N_NODES, 256, 0, stream>>>(p[0], p[1], p[2], p[3], li + 1,
                                          fA, facc, biasp, splitp, MNp, FC[li],
                                          lp.K, Kp, fs, fd, afb, es, ebd);
        if (li < 3) {
            if ((Kp >> 1) <= 256)
                k_gag<1><<<N_NODES, 256, 0, stream>>>(es, ebd, rowp, ssrc, cbuf[li], afb,
                                                      g, cbuf[li + 1], Kp);
            else
                k_gag<2><<<N_NODES, 256, 0, stream>>>(es, ebd, rowp, ssrc, cbuf[li], afb,
                                                      g, cbuf[li + 1], Kp);
            k_gemm_s<<<dim3(lp.C / 128, (N_NODES + 127) / 128, lp.split), 256, 0, stream>>>(
                g, Tb[li], facc, N_NODES, KK, lp.C, KK / lp.split);
        } else {
            k_final<<<(N_NODES + 3) / 4, 256, 0, stream>>>(es, ebd, rowp, ssrc, cbuf[3],
                                                           (float*)d_out);
        }
    }
}